// Round 7
// baseline (99.576 us; speedup 1.0000x reference)
//
#include <hip/hip_runtime.h>

typedef __attribute__((ext_vector_type(8))) short short8;
typedef __attribute__((ext_vector_type(16))) float f32x16;

#define NB 8192        // points per (batch, set); B=4
#define JT_REAL 256    // 32-point j-tiles per (set,b)
#define JT_PAD  258    // +2 pad tiles for prefetch overrun (d = +BIG there)
#define JC 8           // j-splits per (dir,b): chunk = 32 tiles
#define ONE_BF 0x3F80
#define BIG_BF 0x7F7F

__device__ inline unsigned short bf_rne(float f) {
    unsigned u = __float_as_uint(f);
    return (unsigned short)((u + 0x7fffu + ((u >> 16) & 1u)) >> 16);
}
__device__ inline float bf_up(unsigned short h) { return __uint_as_float(((unsigned)h) << 16); }

// Phase 0: build B-operand fragments (MFMA 32x32x16 lane order) for both
// search sets; init minws (0x7F7F7F7F) and out (0).
// K-slot content (half = lane>>5, n = lane&31, point q = jtile*32+n):
//   half0 k0..7 : [(-2qx)_hi,(-2qx)_lo,(-2qy)_hi,(-2qy)_lo,(-2qz)_hi,(-2qz)_lo,|q|2_hi,|q|2_lo]
//   half1 k8..15: [(-2qx)_hi,(-2qy)_hi,(-2qz)_hi, 1.0, 1.0, 0,0,0]
// Pad tiles: half0 slot6 = BIG (so d = 1.0*BIG, never the min).
__global__ __launch_bounds__(256) void pack_kernel(
    const float* __restrict__ xyz1, const float* __restrict__ xyz2,
    short8* __restrict__ bfrag, int* __restrict__ minws, float* __restrict__ out)
{
    int t = blockIdx.x * 256 + threadIdx.x;
    const int FRAGS = 8 * JT_PAD * 64;
    if (t < FRAGS) {
        int lane = t & 63;
        int jt   = (t >> 6) % JT_PAD;
        int sb   = t / (64 * JT_PAD);     // set*4 + b ; set0 = xyz2 (search for dir0)
        int set = sb >> 2, b = sb & 3;
        int n = lane & 31, half = lane >> 5;
        short8 v = {0, 0, 0, 0, 0, 0, 0, 0};
        if (jt >= JT_REAL) {
            if (half == 0) v[6] = (short)BIG_BF;
        } else {
            const float* src = (set == 0) ? xyz2 : xyz1;
            const float* q = src + ((size_t)b * NB + (size_t)jt * 32 + n) * 3;
            float x = q[0], y = q[1], z = q[2];
            float mx = -2.f * x, my = -2.f * y, mz = -2.f * z;
            float qsq = x * x + y * y + z * z;
            unsigned short mhx = bf_rne(mx), mhy = bf_rne(my), mhz = bf_rne(mz);
            if (half == 0) {
                unsigned short mlx = bf_rne(mx - bf_up(mhx));
                unsigned short mly = bf_rne(my - bf_up(mhy));
                unsigned short mlz = bf_rne(mz - bf_up(mhz));
                unsigned short qh  = bf_rne(qsq);
                unsigned short ql  = bf_rne(qsq - bf_up(qh));
                v[0] = (short)mhx; v[1] = (short)mlx;
                v[2] = (short)mhy; v[3] = (short)mly;
                v[4] = (short)mhz; v[5] = (short)mlz;
                v[6] = (short)qh;  v[7] = (short)ql;
            } else {
                v[0] = (short)mhx; v[1] = (short)mhy; v[2] = (short)mhz;
                v[3] = (short)ONE_BF; v[4] = (short)ONE_BF;
            }
        }
        bfrag[t] = v;
    }
    if (t < 2 * 4 * NB) minws[t] = 0x7F7F7F7F;
    if (t == 0) out[0] = 0.f;
}

// Phase 1: MFMA distance tiles + running min.
// Wave owns 128 rows (4 row-tiles of 32) => each loaded B-fragment feeds
// 4 MFMAs (L2 traffic 128 MB total vs 256 MB at 2 row-tiles).
// A-operand (in-register):
//   half0 k0..7 : [px_hi,px_hi,py_hi,py_hi,pz_hi,pz_hi, 1.0, 1.0]
//   half1 k8..15: [px_lo,py_lo,pz_lo,|p|2_hi,|p|2_lo, 0,0,0]
// => D = -2p.q + |q|2 + |p|2 = d^2 directly (error ~1e-5 from dropped lo*lo).
// Grid (16, 8, 8) = 1024 blocks = 4 blocks/CU; (256,4) caps VGPR at 128 so
// all 4 blocks are resident (4 waves/SIMD) in one clean round.
__global__ __launch_bounds__(256, 4) void chamfer_mfma_kernel(
    const float* __restrict__ xyz1, const float* __restrict__ xyz2,
    const short8* __restrict__ bfrag, int* __restrict__ minws)
{
    const int z    = blockIdx.z;        // dir*4 + b
    const int dir  = z >> 2;
    const int b    = z & 3;
    const int lane = threadIdx.x & 63;
    const int w    = threadIdx.x >> 6;
    const int half = lane >> 5;
    const int m    = lane & 31;

    const float* __restrict__ P = (dir == 0) ? xyz1 : xyz2;   // query set

    const int rowbase = blockIdx.x * 512 + w * 128;
    short8 a[4];
    #pragma unroll
    for (int t = 0; t < 4; ++t) {
        const float* p = P + ((size_t)b * NB + rowbase + t * 32 + m) * 3;
        float x = p[0], y = p[1], zc = p[2];
        float psq = x * x + y * y + zc * zc;
        unsigned short hx = bf_rne(x), hy = bf_rne(y), hz = bf_rne(zc);
        short8 v = {0, 0, 0, 0, 0, 0, 0, 0};
        if (half == 0) {
            v[0] = (short)hx; v[1] = (short)hx;
            v[2] = (short)hy; v[3] = (short)hy;
            v[4] = (short)hz; v[5] = (short)hz;
            v[6] = (short)ONE_BF; v[7] = (short)ONE_BF;
        } else {
            unsigned short lx = bf_rne(x - bf_up(hx));
            unsigned short ly = bf_rne(y - bf_up(hy));
            unsigned short lz = bf_rne(zc - bf_up(hz));
            unsigned short ph = bf_rne(psq);
            unsigned short pl = bf_rne(psq - bf_up(ph));
            v[0] = (short)lx; v[1] = (short)ly; v[2] = (short)lz;
            v[3] = (short)ph; v[4] = (short)pl;
        }
        a[t] = v;
    }

    float rmn[4][16];
    #pragma unroll
    for (int t = 0; t < 4; ++t)
        #pragma unroll
        for (int r = 0; r < 16; ++r) rmn[t][r] = 3.4e38f;

    const f32x16 zero16 = {0,0,0,0,0,0,0,0,0,0,0,0,0,0,0,0};

    const short8* __restrict__ bp = bfrag + (size_t)z * JT_PAD * 64;
    const int j0 = blockIdx.y * (JT_REAL / JC);     // 32 tiles per j-chunk

    short8 f0 = bp[(size_t)(j0 + 0) * 64 + lane];
    short8 f1 = bp[(size_t)(j0 + 1) * 64 + lane];
    for (int jt = j0; jt < j0 + JT_REAL / JC; jt += 2) {
        short8 g0 = bp[(size_t)(jt + 2) * 64 + lane];   // pad tiles cover overrun
        short8 g1 = bp[(size_t)(jt + 3) * 64 + lane];
        #pragma unroll
        for (int t = 0; t < 4; ++t) {
            f32x16 d0 = __builtin_amdgcn_mfma_f32_32x32x16_bf16(a[t], f0, zero16, 0, 0, 0);
            f32x16 d1 = __builtin_amdgcn_mfma_f32_32x32x16_bf16(a[t], f1, zero16, 0, 0, 0);
            #pragma unroll
            for (int r = 0; r < 16; ++r)
                rmn[t][r] = fminf(rmn[t][r], fminf(d0[r], d1[r]));  // v_min3
        }
        f0 = g0; f1 = g1;
    }

    // min across the 32 lanes of each half (the j-columns)
    #pragma unroll
    for (int t = 0; t < 4; ++t)
        #pragma unroll
        for (int r = 0; r < 16; ++r) {
            float v = rmn[t][r];
            #pragma unroll
            for (int off = 16; off > 0; off >>= 1)
                v = fminf(v, __shfl_xor(v, off, 32));
            rmn[t][r] = v;
        }

    // C/D row mapping: row = (r&3) + 8*(r>>2) + 4*half  [m74/m101]
    int* __restrict__ base = minws + (dir == 0 ? (size_t)b * NB
                                               : (size_t)4 * NB + (size_t)b * NB);
    if (m == 0) {
        #pragma unroll
        for (int t = 0; t < 4; ++t)
            #pragma unroll
            for (int r = 0; r < 16; ++r) {
                int row = rowbase + t * 32 + 4 * half + (r & 3) + 8 * (r >> 2);
                atomicMin(base + row, __float_as_int(rmn[t][r]));
            }
    }
}

// Phase 2: sum all mins with per-direction scale -> out[0]
__global__ __launch_bounds__(256) void reduce_kernel(
    const int* __restrict__ minws, float* __restrict__ out,
    int BN, int total, float scale1, float scale2)
{
    int t = blockIdx.x * 256 + threadIdx.x;
    float v = 0.f;
    if (t < total)
        v = __int_as_float(minws[t]) * (t < BN ? scale1 : scale2);

    #pragma unroll
    for (int off = 32; off > 0; off >>= 1)
        v += __shfl_down(v, off, 64);

    __shared__ float ssum[4];
    const int lane = threadIdx.x & 63;
    const int wave = threadIdx.x >> 6;
    if (lane == 0) ssum[wave] = v;
    __syncthreads();

    if (threadIdx.x == 0) {
        float s = 0.f;
        #pragma unroll
        for (int wv = 0; wv < 4; ++wv) s += ssum[wv];
        atomicAdd(out, s);
    }
}

extern "C" void kernel_launch(void* const* d_in, const int* in_sizes, int n_in,
                              void* d_out, int out_size, void* d_ws, size_t ws_size,
                              hipStream_t stream) {
    const float* xyz1 = (const float*)d_in[0];
    const float* xyz2 = (const float*)d_in[1];
    float* out = (float*)d_out;

    const int B = 4;
    const int BN = B * NB, BM = B * NB;
    const int total = BN + BM;            // 65536

    // ws: [bfrag: 8*258*64 short8 = 2.06 MB][minws: 64K ints = 256 KB]
    short8* bfrag = (short8*)d_ws;
    int* minws = (int*)(bfrag + (size_t)8 * JT_PAD * 64);

    const int FRAGS = 8 * JT_PAD * 64;    // 132096 = 516*256 exactly
    pack_kernel<<<(FRAGS + 255) / 256, 256, 0, stream>>>(xyz1, xyz2, bfrag, minws, out);

    dim3 grid(16, JC, 2 * B);             // rows/512, j-splits, dir*B+b
    chamfer_mfma_kernel<<<grid, 256, 0, stream>>>(xyz1, xyz2, bfrag, minws);

    const float scale1 = 1.0f / (float)BN;
    const float scale2 = 1.0f / (float)BM;
    reduce_kernel<<<(total + 255) / 256, 256, 0, stream>>>(
        minws, out, BN, total, scale1, scale2);
}